// Round 7
// baseline (23775.186 us; speedup 1.0000x reference)
//
#include <hip/hip_runtime.h>
#include <hip/hip_bf16.h>

typedef __attribute__((ext_vector_type(8))) short short8;
typedef __attribute__((ext_vector_type(4))) float f32x4;
typedef __attribute__((ext_vector_type(4))) unsigned u32x4;

#define T_STEPS 2048
#define HDIM 512
#define SLICE_T (64 * 512)      // elems per time slice
#define NGROUP 8                // batch groups (8 rows each)
#define NSLICE 16               // column slices (32 cols each)
#define SPIN_CAP 500000         // per-step poll budget (hang-proof)

#define MFMA16 __builtin_amdgcn_mfma_f32_16x16x32_bf16
#define ALOAD(p)   __hip_atomic_load((p), __ATOMIC_RELAXED, __HIP_MEMORY_SCOPE_AGENT)
#define ASWAP(p,v) (void)__hip_atomic_exchange((p), (v), __ATOMIC_RELAXED, __HIP_MEMORY_SCOPE_AGENT)

static __device__ __forceinline__ short f2bf(float f) {
    __hip_bfloat16 h = __float2bfloat16(f);
    return __builtin_bit_cast(short, h);
}
static __device__ __forceinline__ float bf2f(short s) {
    unsigned u = ((unsigned)(unsigned short)s) << 16;
    return __builtin_bit_cast(float, u);
}
// pack f32 -> u32 {bf16hi | bf16lo<<16}, lo = bf16(x - hi); exact for +-1.0
static __device__ __forceinline__ unsigned packsplit(float f) {
    short hi = f2bf(f);
    short lo = f2bf(f - bf2f(hi));
    return (unsigned)(unsigned short)hi | ((unsigned)(unsigned short)lo << 16);
}
// epoch tag lives in bit16 (lo-bf16 LSB, numerically ~2^-17 -> negligible)
static __device__ __forceinline__ unsigned tagset(unsigned pk, unsigned e) {
    return (pk & ~(1u << 16)) | (e << 16);
}
// nonzero iff either packed word's tag != e
static __device__ __forceinline__ unsigned tagbad(unsigned long long q, unsigned e) {
    return (((unsigned)(q >> 16) ^ e) & 1u) | (((unsigned)(q >> 48) ^ e) & 1u);
}
static __device__ __forceinline__ void unpack2w(unsigned p0, unsigned p1,
                                                unsigned& hw, unsigned& lw) {
    hw = __builtin_amdgcn_perm(p1, p0, 0x05040100u);
    lw = __builtin_amdgcn_perm(p1, p0, 0x07060302u);
}
union S8U { short8 s8; unsigned u[4]; };
static __device__ __forceinline__ void build8v(u32x4 a, u32x4 b, short8& hi, short8& lo) {
    S8U H, L;
    unpack2w(a[0], a[1], H.u[0], L.u[0]);
    unpack2w(a[2], a[3], H.u[1], L.u[1]);
    unpack2w(b[0], b[1], H.u[2], L.u[2]);
    unpack2w(b[2], b[3], H.u[3], L.u[3]);
    hi = H.s8; lo = L.s8;
}
static __device__ __forceinline__ void split8v(f32x4 u, f32x4 v, short8& hi, short8& lo) {
#pragma unroll
    for (int j = 0; j < 4; ++j) { short h = f2bf(u[j]); hi[j] = h; lo[j] = f2bf(u[j] - bf2f(h)); }
#pragma unroll
    for (int j = 0; j < 4; ++j) { short h = f2bf(v[j]); hi[4+j] = h; lo[4+j] = f2bf(v[j] - bf2f(h)); }
}

// ---------------- Phase 1: xp(t) = input[t] @ Wx + bias -> out[t+1] --------
__global__ __launch_bounds__(256, 2) void rnn_xproj(
    const float* __restrict__ input, const float* __restrict__ weight,
    const float* __restrict__ bias, float* __restrict__ out)
{
    __shared__ unsigned alds[64 * 128];
    __shared__ unsigned wlds[64 * 128];
    const int tid = threadIdx.x, lane = tid & 63, wv = tid >> 6;
    const int t = blockIdx.x >> 3, ct = blockIdx.x & 7;
    const int r16 = lane & 15, kg = lane >> 4, koff = kg * 8;
    const int colt = wv * 16 + r16;
    const int gcol = ct * 64 + colt;
    const float bv = bias[gcol];

    f32x4 acc[4][3];
#pragma unroll
    for (int mt = 0; mt < 4; ++mt) {
        acc[mt][0] = (f32x4){bv, bv, bv, bv};
        acc[mt][1] = (f32x4){0, 0, 0, 0};
        acc[mt][2] = (f32x4){0, 0, 0, 0};
    }

    for (int kq = 0; kq < 4; ++kq) {
        __syncthreads();
        for (int f = tid; f < 64 * 32; f += 256) {
            const int row = f >> 5, sg = f & 31;
            f32x4 v = *(const f32x4*)(input + (size_t)t * SLICE_T + row * HDIM + kq * 128 + sg * 4);
            const unsigned idx = ((unsigned)(row * 128 + sg * 4)) ^ (((unsigned)(row & 7)) << 2);
            u32x4 pk = {packsplit(v[0]), packsplit(v[1]), packsplit(v[2]), packsplit(v[3])};
            *(u32x4*)(&alds[idx]) = pk;
        }
        for (int f = tid; f < 128 * 16; f += 256) {
            const int k = f >> 4, cs = f & 15;
            f32x4 v = *(const f32x4*)(weight + (size_t)(kq * 128 + k) * HDIM + ct * 64 + cs * 4);
#pragma unroll
            for (int j = 0; j < 4; ++j) {
                const int c = cs * 4 + j;
                wlds[((unsigned)(c * 128 + k)) ^ (((unsigned)(c & 7)) << 2)] = packsplit(v[j]);
            }
        }
        __syncthreads();
#pragma unroll
        for (int c2 = 0; c2 < 4; ++c2) {
            const int kp = c2 * 32 + koff;
            const unsigned bi = (unsigned)(colt * 128 + kp), bx = ((unsigned)(colt & 7)) << 2;
            u32x4 qb0 = *(const u32x4*)&wlds[bi ^ bx];
            u32x4 qb1 = *(const u32x4*)&wlds[(bi + 4) ^ bx];
            short8 bhi, blo; build8v(qb0, qb1, bhi, blo);
#pragma unroll
            for (int mt = 0; mt < 4; ++mt) {
                const int row = mt * 16 + r16;
                const unsigned ai = (unsigned)(row * 128 + kp), ax = ((unsigned)(row & 7)) << 2;
                u32x4 qa0 = *(const u32x4*)&alds[ai ^ ax];
                u32x4 qa1 = *(const u32x4*)&alds[(ai + 4) ^ ax];
                short8 ahi, alo; build8v(qa0, qa1, ahi, alo);
                acc[mt][0] = MFMA16(ahi, bhi, acc[mt][0], 0, 0, 0);
                acc[mt][1] = MFMA16(alo, bhi, acc[mt][1], 0, 0, 0);
                acc[mt][2] = MFMA16(ahi, blo, acc[mt][2], 0, 0, 0);
            }
        }
    }
    float* ob = out + (size_t)(t + 1) * SLICE_T;
#pragma unroll
    for (int mt = 0; mt < 4; ++mt)
#pragma unroll
        for (int r = 0; r < 4; ++r)
            ob[(mt * 16 + kg * 4 + r) * HDIM + gcol] =
                acc[mt][0][r] + acc[mt][1][r] + acc[mt][2][r];
}

// ---------------- Phase 2: persistent scan, tag-in-data sync ---------------
// 128 WGs = 8 groups x 16 slices (32 cols), 2 independent waves each.
// Ring words carry their own ready-bit (epoch tag in bit16). Producer: 4
// tagged RMW swaps, nothing else. Consumer: issue all 64 loads pipelined,
// verify per k-block (k-block c == producer slice c), reload stragglers.
// No barriers / canaries / drains in the loop. Slot inits (0x00 / 0xFF)
// guarantee first readers mismatch; epoch parity distinguishes tenant t
// from t-2 / t+2; happens-before chain bounds skew so 1 bit suffices.
__global__ __launch_bounds__(128, 1) void rnn_scan(
    const float* __restrict__ weight, const float* __restrict__ init_h,
    float* __restrict__ out, unsigned* __restrict__ ring)
{
    __shared__ u32x4 whfA[16][2][64];
    __shared__ u32x4 whfB[16][2][64];

    const int tid = threadIdx.x, lane = tid & 63, wv = tid >> 6;
    const int g = blockIdx.x & 7, s = blockIdx.x >> 3;
    const int r16 = lane & 15, kg = lane >> 4, koff = kg * 8;
    const int gcol = s * 32 + wv * 16 + r16;
    const int brow = g * 8 + (r16 & 7);

    // one-time: Wh column-slice B-fragments into LDS
#pragma unroll
    for (int c = 0; c < 16; ++c) {
        unsigned p[8];
#pragma unroll
        for (int j = 0; j < 8; ++j)
            p[j] = packsplit(weight[(size_t)(HDIM + c * 32 + koff + j) * HDIM + gcol]);
        whfA[c][wv][lane] = (u32x4){p[0], p[1], p[2], p[3]};
        whfB[c][wv][lane] = (u32x4){p[4], p[5], p[6], p[7]};
    }
    for (int f = tid; f < 8 * 32; f += 128) {
        const int rr = f >> 5, cc = f & 31;
        out[(size_t)(g * 8 + rr) * HDIM + s * 32 + cc] = init_h[s * 32 + cc];
    }
    __syncthreads();

    bool dead = false;
    for (int t = 0; t < T_STEPS; ++t) {
        const bool has_next = (t + 1 < T_STEPS);
        const unsigned er = ((unsigned)t >> 1) & 1u;        // expected read tag
        const unsigned ew = ((unsigned)(t + 1) >> 1) & 1u;  // write tag

        // xp(t) from out[t+1] (phase-1 data; this WG overwrites it below,
        // ordered by program order + data dependence)
        const float* xpp = out + (size_t)(t + 1) * SLICE_T
                               + (size_t)(g * 8 + (kg & 1) * 4) * HDIM + gcol;
        const float xp0 = xpp[0 * HDIM], xp1 = xpp[1 * HDIM];
        const float xp2 = xpp[2 * HDIM], xp3 = xpp[3 * HDIM];

        f32x4 aA = {0, 0, 0, 0}, aB = {0, 0, 0, 0}, aC = {0, 0, 0, 0};

        if (t == 0) {
#pragma unroll
            for (int c = 0; c < 16; ++c) {
                f32x4 u = *(const f32x4*)(init_h + c * 32 + koff);
                f32x4 v = *(const f32x4*)(init_h + c * 32 + koff + 4);
                short8 ahi, alo; split8v(u, v, ahi, alo);
                short8 bhi, blo; build8v(whfA[c][wv][lane], whfB[c][wv][lane], bhi, blo);
                aA = MFMA16(ahi, bhi, aA, 0, 0, 0);
                aB = MFMA16(alo, bhi, aB, 0, 0, 0);
                aC = MFMA16(ahi, blo, aC, 0, 0, 0);
            }
        } else {
            const unsigned* rb = ring + (t & 1) * SLICE_T + brow * HDIM;
            unsigned long long q[16][4];
            // phase A: issue all 64 loads (pipelined, in flight together)
#pragma unroll
            for (int c = 0; c < 16; ++c) {
                const unsigned* p = rb + c * 32 + koff;
                q[c][0] = ALOAD((const unsigned long long*)(p + 0));
                q[c][1] = ALOAD((const unsigned long long*)(p + 2));
                q[c][2] = ALOAD((const unsigned long long*)(p + 4));
                q[c][3] = ALOAD((const unsigned long long*)(p + 6));
            }
            // phase B: per k-block verify tag, reload stragglers, consume
            int budget = SPIN_CAP;
#pragma unroll
            for (int c = 0; c < 16; ++c) {
                const unsigned* p = rb + c * 32 + koff;
                if (!dead) {
                    for (;;) {
                        const unsigned bad = tagbad(q[c][0], er) | tagbad(q[c][1], er)
                                           | tagbad(q[c][2], er) | tagbad(q[c][3], er);
                        if (!__any((int)bad)) break;
                        if (--budget <= 0) { dead = true; break; }  // hang-proof
                        q[c][0] = ALOAD((const unsigned long long*)(p + 0));
                        q[c][1] = ALOAD((const unsigned long long*)(p + 2));
                        q[c][2] = ALOAD((const unsigned long long*)(p + 4));
                        q[c][3] = ALOAD((const unsigned long long*)(p + 6));
                    }
                }
                S8U hh, hl;
                unpack2w((unsigned)q[c][0], (unsigned)(q[c][0] >> 32), hh.u[0], hl.u[0]);
                unpack2w((unsigned)q[c][1], (unsigned)(q[c][1] >> 32), hh.u[1], hl.u[1]);
                unpack2w((unsigned)q[c][2], (unsigned)(q[c][2] >> 32), hh.u[2], hl.u[2]);
                unpack2w((unsigned)q[c][3], (unsigned)(q[c][3] >> 32), hh.u[3], hl.u[3]);
                short8 bhi, blo; build8v(whfA[c][wv][lane], whfB[c][wv][lane], bhi, blo);
                aA = MFMA16(hh.s8, bhi, aA, 0, 0, 0);
                aB = MFMA16(hl.s8, bhi, aB, 0, 0, 0);
                aC = MFMA16(hh.s8, blo, aC, 0, 0, 0);
            }
        }

        const float hn0 = tanhf(aA[0] + aB[0] + aC[0] + xp0);
        const float hn1 = tanhf(aA[1] + aB[1] + aC[1] + xp1);
        const float hn2 = tanhf(aA[2] + aB[2] + aC[2] + xp2);
        const float hn3 = tanhf(aA[3] + aB[3] + aC[3] + xp3);

        // post h_{t+1}: tagged RMW swaps — the signal IS the data
        if (kg < 2 && has_next) {
            unsigned* wb = ring + ((t + 1) & 1) * SLICE_T
                                + (size_t)(g * 8 + kg * 4) * HDIM + gcol;
            ASWAP(&wb[0 * HDIM], tagset(packsplit(hn0), ew));
            ASWAP(&wb[1 * HDIM], tagset(packsplit(hn1), ew));
            ASWAP(&wb[2 * HDIM], tagset(packsplit(hn2), ew));
            ASWAP(&wb[3 * HDIM], tagset(packsplit(hn3), ew));
        }
        // off critical path: final f32 h to out[t+1]
        if (kg < 2) {
            float* op = out + (size_t)(t + 1) * SLICE_T
                            + (size_t)(g * 8 + kg * 4) * HDIM + gcol;
            __builtin_nontemporal_store(hn0, op + 0 * HDIM);
            __builtin_nontemporal_store(hn1, op + 1 * HDIM);
            __builtin_nontemporal_store(hn2, op + 2 * HDIM);
            __builtin_nontemporal_store(hn3, op + 3 * HDIM);
        }
    }
}

extern "C" void kernel_launch(void* const* d_in, const int* in_sizes, int n_in,
                              void* d_out, int out_size, void* d_ws, size_t ws_size,
                              hipStream_t stream) {
    const float* input  = (const float*)d_in[0];
    const float* weight = (const float*)d_in[1];
    const float* biasp  = (const float*)d_in[2];
    const float* inith  = (const float*)d_in[3];
    float* out = (float*)d_out;

    // slot inits: first reader of slot0 (t=2) expects tag 1 -> init tag 0;
    // first reader of slot1 (t=1) expects tag 0 -> init tag 1. Re-done every
    // call -> graph-replay deterministic.
    hipMemsetAsync(d_ws, 0x00, SLICE_T * 4, stream);
    hipMemsetAsync((char*)d_ws + SLICE_T * 4, 0xFF, SLICE_T * 4, stream);

    rnn_xproj<<<dim3(T_STEPS * 8), dim3(256), 0, stream>>>(input, weight, biasp, out);
    rnn_scan<<<dim3(NGROUP * NSLICE), dim3(128), 0, stream>>>(
        weight, inith, out, (unsigned*)d_ws);
}